// Round 6
// baseline (30.750 us; speedup 1.0000x reference)
//
#include <hip/hip_runtime.h>
#include <hip/hip_bf16.h>

// FFM: out[b] = x_b . w_lin + b_lin + sum_{i<j} x_i W_ij x_j
// W_ij = dot(v[i, f_j, :], v[j, f_i, :])  (symmetric)
// M = 0.5*(Wu + Wu^T), zero diag, bf16, packed in MFMA B-fragment order.
// out = x . (M x + w) + b via 16x16x32 bf16 MFMA.
// R5 = R4 + fix: stage FULL 16x256 tile (2 float4/thread; R4 staged only
//     cols 0..127 -> absmax 2632). M in LDS keeps compute vmcnt-free so the
//     x prefetch overlaps MFMA.

#define FK 256   // F*K = 32*8

typedef __attribute__((ext_vector_type(8))) short bf16x8;
typedef __attribute__((ext_vector_type(4))) float f32x4v;

__device__ __forceinline__ unsigned short f2bf(float x) {
    return __builtin_bit_cast(unsigned short, __float2bfloat16(x));
}
__device__ __forceinline__ float bf2f(unsigned short h) {
    return __builtin_bit_cast(float, (unsigned int)h << 16);
}

template<int CTRL>
__device__ __forceinline__ float dppadd(float v) {
    int t = __builtin_amdgcn_update_dpp(0, __builtin_bit_cast(int, v),
                                        CTRL, 0xf, 0xf, true);
    return v + __builtin_bit_cast(float, t);
}

// ---------------- Kernel 1: build packed M (bf16, B-fragment order) --------
// mpack uint4 element ((s*16 + ct)*64 + l), lane-elem i = M[k][c],
//   k = s*32 + ((l>>4)&3)*8 + i,  c = ct*16 + (l&15)
__global__ __launch_bounds__(256) void k_build_m(
    const float* __restrict__ v, const int* __restrict__ fidx,
    uint4* __restrict__ mpack)
{
    __shared__ int fsh[256];
    int tid = threadIdx.x;
    fsh[tid] = fidx[tid];
    __syncthreads();

    int t = blockIdx.x * 256 + tid;           // 8192 threads
    int l  = t & 63;
    int ct = (t >> 6) & 15;
    int s  = t >> 10;                          // 0..7
    int c  = ct * 16 + (l & 15);
    int k0 = s * 32 + ((l >> 4) & 3) * 8;
    int fc = fsh[c];
    unsigned short h[8];
#pragma unroll
    for (int i = 0; i < 8; ++i) {
        int k = k0 + i;
        float acc = 0.f;
        if (k != c) {
            int fk = fsh[k];
            const float* va = v + k * FK + fc * 8;   // v[k, f_c, :]
            const float* vb = v + c * FK + fk * 8;   // v[c, f_k, :]
#pragma unroll
            for (int j = 0; j < 8; ++j) acc += va[j] * vb[j];
            acc *= 0.5f;
        }
        h[i] = f2bf(acc);
    }
    uint4 o;
    o.x = (unsigned int)h[0] | ((unsigned int)h[1] << 16);
    o.y = (unsigned int)h[2] | ((unsigned int)h[3] << 16);
    o.z = (unsigned int)h[4] | ((unsigned int)h[5] << 16);
    o.w = (unsigned int)h[6] | ((unsigned int)h[7] << 16);
    mpack[t] = o;
}

// ---------------- Kernel 2: main --------------------------------------------
// 256 blocks x 512 threads (8 waves). Wave w owns cols [w*32, w*32+32).
// x tile: 16 rows x 256 cols bf16 in LDS, row stride 512 B, 16B chunks
// XOR-swizzled by ((row&7)<<4). M: LDS, B-frag packed (lane-linear 16B).

struct SmemT {
    unsigned short M[65536];        // 128 KB
    unsigned short xs[2][4096];     // 2 x 8 KB
    float part[8][16];
};

__device__ __forceinline__ void stage_write(unsigned short* buf, float4 val,
                                            int row, int chunk) {
    unsigned long long h0 = f2bf(val.x), h1 = f2bf(val.y),
                       h2 = f2bf(val.z), h3 = f2bf(val.w);
    unsigned long long pk = h0 | (h1 << 16) | (h2 << 32) | (h3 << 48);
    int byteoff = row * 512 + ((chunk * 8) ^ ((row & 7) << 4));
    *(unsigned long long*)((char*)buf + byteoff) = pk;
}

__device__ __forceinline__ void compute_tile(
    const unsigned short* xsbuf, const unsigned short* Msh,
    float w0, float w1, float (*part)[16], int w, int l, int l15, int lg)
{
    const char* xsb = (const char*)xsbuf;
    const char* mb  = (const char*)Msh;

    f32x4v acc0 = {w0, w0, w0, w0};
    f32x4v acc1 = {w1, w1, w1, w1};

    // GEMM: acc = w + X_tile(16x256) @ M(:, wave cols)
#pragma unroll
    for (int s = 0; s < 8; ++s) {
        int aoff = l15 * 512 + ((s * 64 + lg * 16) ^ ((l15 & 7) << 4));
        bf16x8 af = *(const bf16x8*)(xsb + aoff);
        bf16x8 b0 = *(const bf16x8*)(mb + (((s * 16 + w * 2 + 0) * 64 + l) << 4));
        bf16x8 b1 = *(const bf16x8*)(mb + (((s * 16 + w * 2 + 1) * 64 + l) << 4));
        acc0 = __builtin_amdgcn_mfma_f32_16x16x32_bf16(af, b0, acc0, 0, 0, 0);
        acc1 = __builtin_amdgcn_mfma_f32_16x16x32_bf16(af, b1, acc1, 0, 0, 0);
    }

    // dot: p[row] = sum_{cols of wave} x[row][col] * acc;  C/D layout:
    // col = ct*16 + (lane&15), row = (lane>>4)*4 + reg
#pragma unroll
    for (int r = 0; r < 4; ++r) {
        int row = lg * 4 + r;
        int sw  = (row & 7) << 4;
        int c0  = (w * 2 + 0) * 16 + l15;
        int c1  = (w * 2 + 1) * 16 + l15;
        unsigned short h0 = *(const unsigned short*)(xsb + row * 512 + ((c0 * 2) ^ sw));
        unsigned short h1 = *(const unsigned short*)(xsb + row * 512 + ((c1 * 2) ^ sw));
        float pp = bf2f(h0) * acc0[r] + bf2f(h1) * acc1[r];
        pp = dppadd<0x121>(pp); pp = dppadd<0x122>(pp);
        pp = dppadd<0x124>(pp); pp = dppadd<0x128>(pp);
        if (l15 == 0) part[w][row] = pp;
    }
}

__global__ __launch_bounds__(512, 1) void k_main(
    const float* __restrict__ x, const float* __restrict__ w_lin,
    const float* __restrict__ b_lin, const uint4* __restrict__ mpack,
    float* __restrict__ out)
{
    __shared__ SmemT sm;

    const int tid = threadIdx.x;
    const int w   = tid >> 6;        // 0..7
    const int l   = tid & 63;
    const int l15 = l & 15;
    const int lg  = l >> 4;          // 0..3

    // ---- prologue: M -> LDS (L2/L3-resident, 16 uint4/thread) ----
    {
        uint4* md = (uint4*)sm.M;
#pragma unroll
        for (int j = 0; j < 16; ++j)
            md[j * 512 + tid] = mpack[j * 512 + tid];
    }
    float w0 = w_lin[(w * 2 + 0) * 16 + l15];
    float w1 = w_lin[(w * 2 + 1) * 16 + l15];
    float bv = b_lin[0];

    const long rowbase = (long)blockIdx.x * 256;   // 256 rows per block
    const float* xg = x + rowbase * 256;

    const int srow = w * 2 + (l >> 5);   // row in tile this lane stages
    const int sc0  = l & 31;             // first 16B chunk
    const int sc1  = sc0 + 32;           // second 16B chunk

    // ---- prologue: prefetch tile 0 (full row: 2 float4 per lane) ----
    float4 preA0 = *(const float4*)(xg + srow * 256 + sc0 * 4);
    float4 preA1 = *(const float4*)(xg + srow * 256 + sc1 * 4);

    for (int tt = 0; tt < 8; ++tt) {
        const int t0 = tt * 2, t1 = tt * 2 + 1;

        // ---- tile t0 (buf 0) ----
        stage_write(sm.xs[0], preA0, srow, sc0);
        stage_write(sm.xs[0], preA1, srow, sc1);
        float4 preB0 = *(const float4*)(xg + (t1 * 16 + srow) * 256 + sc0 * 4);
        float4 preB1 = *(const float4*)(xg + (t1 * 16 + srow) * 256 + sc1 * 4);
        __syncthreads();
        compute_tile(sm.xs[0], sm.M, w0, w1, sm.part, w, l, l15, lg);
        __syncthreads();
        if (tid < 16) {
            float y = sm.part[0][tid] + sm.part[1][tid] + sm.part[2][tid] +
                      sm.part[3][tid] + sm.part[4][tid] + sm.part[5][tid] +
                      sm.part[6][tid] + sm.part[7][tid];
            out[rowbase + t0 * 16 + tid] = y + bv;
        }

        // ---- tile t1 (buf 1) ----
        stage_write(sm.xs[1], preB0, srow, sc0);
        stage_write(sm.xs[1], preB1, srow, sc1);
        if (tt < 7) {
            preA0 = *(const float4*)(xg + ((tt * 2 + 2) * 16 + srow) * 256 + sc0 * 4);
            preA1 = *(const float4*)(xg + ((tt * 2 + 2) * 16 + srow) * 256 + sc1 * 4);
        }
        __syncthreads();
        compute_tile(sm.xs[1], sm.M, w0, w1, sm.part, w, l, l15, lg);
        __syncthreads();
        if (tid < 16) {
            float y = sm.part[0][tid] + sm.part[1][tid] + sm.part[2][tid] +
                      sm.part[3][tid] + sm.part[4][tid] + sm.part[5][tid] +
                      sm.part[6][tid] + sm.part[7][tid];
            out[rowbase + t1 * 16 + tid] = y + bv;
        }
    }
}

extern "C" void kernel_launch(void* const* d_in, const int* in_sizes, int n_in,
                              void* d_out, int out_size, void* d_ws, size_t ws_size,
                              hipStream_t stream) {
    const float* x     = (const float*)d_in[0];
    const float* w_lin = (const float*)d_in[1];
    const float* b_lin = (const float*)d_in[2];
    const float* v     = (const float*)d_in[3];
    const int*   fidx  = (const int*)d_in[4];
    float* out = (float*)d_out;
    uint4* mpack = (uint4*)d_ws;   // 128 KB

    k_build_m<<<32, 256, 0, stream>>>(v, fidx, mpack);
    k_main<<<256, 512, 0, stream>>>(x, w_lin, b_lin, mpack, out);
}

// Round 7
// 23.695 us; speedup vs baseline: 1.2977x; 1.2977x over previous
//
#include <hip/hip_runtime.h>
#include <hip/hip_bf16.h>

// FFM: out[b] = x_b . w_lin + b_lin + sum_{i<j} x_i W_ij x_j
// W_ij = dot(v[i, f_j, :], v[j, f_i, :])  (symmetric)
// M = 0.5*(Wu + Wu^T), zero diag, bf16, packed in MFMA B-fragment order.
// out = x . (M x + w) + b via 16x16x32 bf16 MFMA.
// R6: B-fragments in REGISTERS (64 VGPR/lane, loaded once) -> compute is
//     vmcnt-free AND B-LDS-free. LDS = 17 KB -> 2 blocks/CU overlap.
//     512 blocks x 128 rows, 8 tiles x 16 rows, 1 barrier per tile.

#define FK 256   // F*K = 32*8

typedef __attribute__((ext_vector_type(8))) short bf16x8;
typedef __attribute__((ext_vector_type(4))) float f32x4v;

__device__ __forceinline__ unsigned short f2bf(float x) {
    return __builtin_bit_cast(unsigned short, __float2bfloat16(x));
}
__device__ __forceinline__ float bf2f(unsigned short h) {
    return __builtin_bit_cast(float, (unsigned int)h << 16);
}

template<int CTRL>
__device__ __forceinline__ float dppadd(float v) {
    int t = __builtin_amdgcn_update_dpp(0, __builtin_bit_cast(int, v),
                                        CTRL, 0xf, 0xf, true);
    return v + __builtin_bit_cast(float, t);
}

// ---------------- Kernel 1: build packed M (bf16, B-fragment order) --------
// mpack uint4 element ((s*16 + ct)*64 + l), lane-elem i = M[k][c],
//   k = s*32 + ((l>>4)&3)*8 + i,  c = ct*16 + (l&15)
// One thread produces a uint2 (4 elems, h = which half).
__global__ __launch_bounds__(64) void k_build_m(
    const float* __restrict__ v, const int* __restrict__ fidx,
    uint2* __restrict__ mpack2)
{
    int t = blockIdx.x * 64 + threadIdx.x;    // 16384 threads
    int h  = t & 1;
    int l  = (t >> 1) & 63;
    int ct = (t >> 7) & 15;
    int s  = t >> 11;                          // 0..7
    int c  = ct * 16 + (l & 15);
    int k0 = s * 32 + ((l >> 4) & 3) * 8 + h * 4;
    int fc = fidx[c];
    unsigned short hh[4];
#pragma unroll
    for (int i = 0; i < 4; ++i) {
        int k = k0 + i;
        float acc = 0.f;
        if (k != c) {
            int fk = fidx[k];
            const float* va = v + k * FK + fc * 8;   // v[k, f_c, :]
            const float* vb = v + c * FK + fk * 8;   // v[c, f_k, :]
#pragma unroll
            for (int j = 0; j < 8; ++j) acc += va[j] * vb[j];
            acc *= 0.5f;
        }
        hh[i] = f2bf(acc);
    }
    uint2 o;
    o.x = (unsigned int)hh[0] | ((unsigned int)hh[1] << 16);
    o.y = (unsigned int)hh[2] | ((unsigned int)hh[3] << 16);
    mpack2[t] = o;
}

// ---------------- Kernel 2: main --------------------------------------------
// 512 blocks x 512 threads (8 waves), 128 rows/block, 8 tiles x 16 rows.
// Wave w owns cols [w*32, w*32+32); its B-fragments live in registers.
// x tile: 16 rows x 256 cols bf16, row stride 512 B, 16B chunks XOR-swizzled
// by ((row&7)<<4).

struct SmemT {
    unsigned short xs[2][4096];     // 2 x 8 KB
    float part[2][8][16];           // 1 KB, double-buffered
};

__device__ __forceinline__ void stage_write(unsigned short* buf, float4 val,
                                            int row, int chunk) {
    unsigned long long h0 = f2bf(val.x), h1 = f2bf(val.y),
                       h2 = f2bf(val.z), h3 = f2bf(val.w);
    unsigned long long pk = h0 | (h1 << 16) | (h2 << 32) | (h3 << 48);
    int byteoff = row * 512 + ((chunk * 8) ^ ((row & 7) << 4));
    *(unsigned long long*)((char*)buf + byteoff) = pk;
}

__global__ __launch_bounds__(512, 4) void k_main(
    const float* __restrict__ x, const float* __restrict__ w_lin,
    const float* __restrict__ b_lin, const uint4* __restrict__ mpack,
    float* __restrict__ out)
{
    __shared__ SmemT sm;

    const int tid = threadIdx.x;
    const int w   = tid >> 6;        // 0..7
    const int l   = tid & 63;
    const int l15 = l & 15;
    const int lg  = l >> 4;          // 0..3

    // ---- prologue: this wave's B-fragments -> registers (16 x uint4) ----
    bf16x8 Brg[8][2];
#pragma unroll
    for (int s = 0; s < 8; ++s)
#pragma unroll
        for (int ct = 0; ct < 2; ++ct)
            Brg[s][ct] = __builtin_bit_cast(bf16x8,
                mpack[(s * 16 + w * 2 + ct) * 64 + l]);

    const float w0 = w_lin[(w * 2 + 0) * 16 + l15];
    const float w1 = w_lin[(w * 2 + 1) * 16 + l15];
    const float bv = b_lin[0];

    const long rowbase = (long)blockIdx.x * 128;   // 128 rows per block
    const float* xg = x + rowbase * 256;

    const int srow = w * 2 + (l >> 5);   // row in tile this lane stages
    const int sc0  = l & 31;             // first 16B chunk
    const int sc1  = sc0 + 32;           // second 16B chunk

    // ---- prologue: tile 0 staged, tile 1 prefetched ----
    float4 pa = *(const float4*)(xg + srow * 256 + sc0 * 4);
    float4 pb = *(const float4*)(xg + srow * 256 + sc1 * 4);
    stage_write(sm.xs[0], pa, srow, sc0);
    stage_write(sm.xs[0], pb, srow, sc1);
    pa = *(const float4*)(xg + (16 + srow) * 256 + sc0 * 4);
    pb = *(const float4*)(xg + (16 + srow) * 256 + sc1 * 4);
    __syncthreads();

    for (int t = 0; t < 8; ++t) {
        const char* xsb = (const char*)sm.xs[t & 1];

        // ---- GEMM: acc = w + X_tile(16x256) @ M(:, wave cols) ----
        f32x4v acc0 = {w0, w0, w0, w0};
        f32x4v acc1 = {w1, w1, w1, w1};
#pragma unroll
        for (int s = 0; s < 8; ++s) {
            int aoff = l15 * 512 + ((s * 64 + lg * 16) ^ ((l15 & 7) << 4));
            bf16x8 af = *(const bf16x8*)(xsb + aoff);
            acc0 = __builtin_amdgcn_mfma_f32_16x16x32_bf16(af, Brg[s][0], acc0, 0, 0, 0);
            acc1 = __builtin_amdgcn_mfma_f32_16x16x32_bf16(af, Brg[s][1], acc1, 0, 0, 0);
        }

        // ---- dot: p[row] = sum_{cols of wave} x[row][col] * acc ----
        // C/D layout (m89): col = ct*16 + (lane&15), row = (lane>>4)*4 + reg
#pragma unroll
        for (int r = 0; r < 4; ++r) {
            int row = lg * 4 + r;
            int sw  = (row & 7) << 4;
            int c0  = (w * 2 + 0) * 16 + l15;
            int c1  = (w * 2 + 1) * 16 + l15;
            unsigned short h0 = *(const unsigned short*)(xsb + row * 512 + ((c0 * 2) ^ sw));
            unsigned short h1 = *(const unsigned short*)(xsb + row * 512 + ((c1 * 2) ^ sw));
            float pp = bf2f(h0) * acc0[r] + bf2f(h1) * acc1[r];
            pp = dppadd<0x121>(pp); pp = dppadd<0x122>(pp);
            pp = dppadd<0x124>(pp); pp = dppadd<0x128>(pp);
            if (l15 == 0) sm.part[t & 1][w][row] = pp;
        }

        // ---- stage tile t+1 into other buffer; prefetch tile t+2 ----
        if (t < 7) {
            unsigned short* nb = sm.xs[(t + 1) & 1];
            stage_write(nb, pa, srow, sc0);
            stage_write(nb, pb, srow, sc1);
        }
        if (t < 6) {
            pa = *(const float4*)(xg + ((t + 2) * 16 + srow) * 256 + sc0 * 4);
            pb = *(const float4*)(xg + ((t + 2) * 16 + srow) * 256 + sc1 * 4);
        }
        __syncthreads();

        if (tid < 16) {
            const float (*pt)[16] = sm.part[t & 1];
            float y = pt[0][tid] + pt[1][tid] + pt[2][tid] + pt[3][tid] +
                      pt[4][tid] + pt[5][tid] + pt[6][tid] + pt[7][tid];
            out[rowbase + t * 16 + tid] = y + bv;
        }
    }
}

extern "C" void kernel_launch(void* const* d_in, const int* in_sizes, int n_in,
                              void* d_out, int out_size, void* d_ws, size_t ws_size,
                              hipStream_t stream) {
    const float* x     = (const float*)d_in[0];
    const float* w_lin = (const float*)d_in[1];
    const float* b_lin = (const float*)d_in[2];
    const float* v     = (const float*)d_in[3];
    const int*   fidx  = (const int*)d_in[4];
    float* out = (float*)d_out;
    void* mpack = d_ws;   // 128 KB

    k_build_m<<<256, 64, 0, stream>>>(v, fidx, (uint2*)mpack);
    k_main<<<512, 512, 0, stream>>>(x, w_lin, b_lin, (const uint4*)mpack, out);
}